// Round 7
// baseline (280.556 us; speedup 1.0000x reference)
//
#include <hip/hip_runtime.h>

#define N_NODES 50000
#define N_EDGES 800000
#define IN_FEATS 256
#define HIDDEN 128
#define OUT_FEATS 64

// ---- LDS-histogram decomposition (packed u16 counters) ----
#define NB 16384             // bins per range (2 bins/u32 word -> 32 KB LDS)
#define NRANGE 4             // ceil(50000/16384)
#define NBT (NRANGE * NB)    // 65536 padded bins per copy (u16 each)
#define NCHUNK 64            // edge chunks (= privatized copies)
#define EPC 12500            // edges per chunk; per-bin count <= 12500 < 2^16

typedef _Float16 f16;
typedef _Float16 f16x8 __attribute__((ext_vector_type(8)));
typedef float f32x4 __attribute__((ext_vector_type(4)));

// ---------------------------------------------------------- LDS histogram
// Zero global atomics (gfx950 global atomics cost ~32B beyond-L2 traffic
// each regardless of locality — measured R3/R4). u16 counters packed two
// per u32; no cross-half carry since per-chunk bin count <= EPC=12500.
__global__ __launch_bounds__(256) void hist_kernel(
    const int* __restrict__ src, const int* __restrict__ dst,
    unsigned* __restrict__ hist_src, unsigned* __restrict__ hist_dst) {
  __shared__ unsigned ls[NB / 2];   // 32 KB
  __shared__ unsigned ld2[NB / 2];  // 32 KB
  const int r = blockIdx.x % NRANGE;
  const int c = blockIdx.x / NRANGE;
  const int lo = r * NB;
  for (int i = threadIdx.x; i < NB / 2; i += 256) {
    ls[i] = 0;
    ld2[i] = 0;
  }
  __syncthreads();
  const int4* s4 = (const int4*)(src + c * EPC);
  const int4* d4 = (const int4*)(dst + c * EPC);
  for (int i = threadIdx.x; i < EPC / 4; i += 256) {
    int4 s = s4[i];
    int4 d = d4[i];
    unsigned b;
    b = (unsigned)(s.x - lo); if (b < NB) atomicAdd(&ls[b >> 1], 1u << ((b & 1) << 4));
    b = (unsigned)(s.y - lo); if (b < NB) atomicAdd(&ls[b >> 1], 1u << ((b & 1) << 4));
    b = (unsigned)(s.z - lo); if (b < NB) atomicAdd(&ls[b >> 1], 1u << ((b & 1) << 4));
    b = (unsigned)(s.w - lo); if (b < NB) atomicAdd(&ls[b >> 1], 1u << ((b & 1) << 4));
    b = (unsigned)(d.x - lo); if (b < NB) atomicAdd(&ld2[b >> 1], 1u << ((b & 1) << 4));
    b = (unsigned)(d.y - lo); if (b < NB) atomicAdd(&ld2[b >> 1], 1u << ((b & 1) << 4));
    b = (unsigned)(d.z - lo); if (b < NB) atomicAdd(&ld2[b >> 1], 1u << ((b & 1) << 4));
    b = (unsigned)(d.w - lo); if (b < NB) atomicAdd(&ld2[b >> 1], 1u << ((b & 1) << 4));
  }
  __syncthreads();
  unsigned* hs = hist_src + ((long)c * NBT + lo) / 2;
  unsigned* hd = hist_dst + ((long)c * NBT + lo) / 2;
  for (int i = threadIdx.x; i < NB / 2; i += 256) {
    hs[i] = ls[i];
    hd[i] = ld2[i];
  }
}

// sum copies -> norms; hist_dst -> exclusive prefix over copies (u16; max
// in-degree for this input ~50, far below 2^16); emits per-block degree sums.
__global__ __launch_bounds__(256) void reduce_kernel(
    const unsigned* __restrict__ hist_src, unsigned* __restrict__ hist_dst,
    int* __restrict__ deg_in, float* __restrict__ norm_src,
    float* __restrict__ norm_dst, int* __restrict__ partial) {
  const unsigned short* hs = (const unsigned short*)hist_src;
  unsigned short* hd = (unsigned short*)hist_dst;
  int n = blockIdx.x * 256 + threadIdx.x;
  int run = 0;
  if (n < N_NODES) {
    int so = 0;
#pragma unroll 8
    for (int c = 0; c < NCHUNK; ++c) so += hs[(long)c * NBT + n];
    norm_src[n] = rsqrtf((float)max(so, 1));
#pragma unroll 8
    for (int c = 0; c < NCHUNK; ++c) {
      int t = hd[(long)c * NBT + n];
      hd[(long)c * NBT + n] = (unsigned short)run;
      run += t;
    }
    deg_in[n] = run;
    norm_dst[n] = rsqrtf((float)max(run, 1));
  }
  __shared__ int sd[256];
  sd[threadIdx.x] = run;
  __syncthreads();
  for (int s = 128; s > 0; s >>= 1) {
    if (threadIdx.x < s) sd[threadIdx.x] += sd[threadIdx.x + s];
    __syncthreads();
  }
  if (threadIdx.x == 0) partial[blockIdx.x] = sd[0];
}

// ------------------------------------------------------------- prefix scan
__global__ __launch_bounds__(256) void scan2(int* __restrict__ partial,
                                             int nb) {
  __shared__ int sd[256];
  int v = (threadIdx.x < nb) ? partial[threadIdx.x] : 0;
  sd[threadIdx.x] = v;
  __syncthreads();
  for (int off = 1; off < 256; off <<= 1) {
    int t = sd[threadIdx.x] +
            ((threadIdx.x >= off) ? sd[threadIdx.x - off] : 0);
    __syncthreads();
    sd[threadIdx.x] = t;
    __syncthreads();
  }
  if (threadIdx.x < nb) partial[threadIdx.x] = sd[threadIdx.x] - v;  // excl
}

__global__ __launch_bounds__(256) void scan3(const int* __restrict__ deg,
                                             const int* __restrict__ partial,
                                             int* __restrict__ rowptr) {
  __shared__ int sd[256];
  int i = blockIdx.x * 256 + threadIdx.x;
  int v = (i < N_NODES) ? deg[i] : 0;
  sd[threadIdx.x] = v;
  __syncthreads();
  for (int off = 1; off < 256; off <<= 1) {
    int t = sd[threadIdx.x] +
            ((threadIdx.x >= off) ? sd[threadIdx.x - off] : 0);
    __syncthreads();
    sd[threadIdx.x] = t;
    __syncthreads();
  }
  if (i < N_NODES) rowptr[i] = partial[blockIdx.x] + sd[threadIdx.x] - v;
  if (blockIdx.x == 0 && threadIdx.x == 0) rowptr[N_NODES] = N_EDGES;
}

// ------------------------------------------------------------- CSR fill
__global__ __launch_bounds__(256) void fill_csr(
    const int* __restrict__ src, const int* __restrict__ dst,
    const int* __restrict__ rowptr, const unsigned* __restrict__ pref32,
    int* __restrict__ col) {
  __shared__ int cur[NB];  // 64 KB
  const unsigned short* pref = (const unsigned short*)pref32;
  const int r = blockIdx.x % NRANGE;
  const int c = blockIdx.x / NRANGE;
  const int lo = r * NB;
  for (int i = threadIdx.x; i < NB; i += 256) {
    int n = lo + i;
    cur[i] = (n < N_NODES) ? rowptr[n] + pref[(long)c * NBT + n] : 0;
  }
  __syncthreads();
  const int4* s4 = (const int4*)(src + c * EPC);
  const int4* d4 = (const int4*)(dst + c * EPC);
  for (int i = threadIdx.x; i < EPC / 4; i += 256) {
    int4 s = s4[i];
    int4 d = d4[i];
    unsigned b;
    b = (unsigned)(d.x - lo);
    if (b < NB) col[atomicAdd(&cur[b], 1)] = s.x;
    b = (unsigned)(d.y - lo);
    if (b < NB) col[atomicAdd(&cur[b], 1)] = s.y;
    b = (unsigned)(d.z - lo);
    if (b < NB) col[atomicAdd(&cur[b], 1)] = s.z;
    b = (unsigned)(d.w - lo);
    if (b < NB) col[atomicAdd(&cur[b], 1)] = s.w;
  }
}

// ------------------------------------------------------------- W transpose
__global__ __launch_bounds__(256) void wtrans(const float* __restrict__ W1,
                                              const float* __restrict__ W2,
                                              f16* __restrict__ W1T,
                                              f16* __restrict__ W2T) {
  int i = blockIdx.x * 256 + threadIdx.x;
  if (i < 128 * 256) {
    int n = i >> 8, k = i & 255;
    W1T[i] = (f16)W1[k * 128 + n];
  } else if (i < 128 * 256 + 64 * 128) {
    int j = i - 128 * 256;
    int n = j >> 7, k = j & 127;
    W2T[j] = (f16)W2[k * 64 + n];
  }
}

// ------------------------------------------------------------- MFMA GEMM
template <int K, int NC, bool FP32IN>
__global__ __launch_bounds__(256) void gemm_mfma(
    const void* __restrict__ Xv, const f16* __restrict__ WT,
    const float* __restrict__ ns, f16* __restrict__ Mout) {
  constexpr int KI = K / 32;
  constexpr int NT = NC / 16;
  const int wave = threadIdx.x >> 6;
  const int lane = threadIdx.x & 63;
  const int m = lane & 15;
  const int q = lane >> 4;
  const int wrow0 = blockIdx.x * 128 + wave * 32;

  const int ra0 = min(wrow0 + m, N_NODES - 1);
  const int ra1 = min(wrow0 + 16 + m, N_NODES - 1);
  const float s0 = FP32IN ? ns[ra0] : 0.f;
  const float s1 = FP32IN ? ns[ra1] : 0.f;

  f32x4 acc[2][NT];
#pragma unroll
  for (int ab = 0; ab < 2; ++ab)
#pragma unroll
    for (int t = 0; t < NT; ++t) acc[ab][t] = (f32x4){0.f, 0.f, 0.f, 0.f};

#pragma unroll
  for (int ki = 0; ki < KI; ++ki) {
    const int kbase = ki * 32 + q * 8;
    f16x8 a0, a1;
    if (FP32IN) {
      const float* X = (const float*)Xv;
      const float* p0 = X + (long)ra0 * K + kbase;
      const float* p1 = X + (long)ra1 * K + kbase;
      float4 u0 = *(const float4*)p0;
      float4 u1 = *(const float4*)(p0 + 4);
      float4 w0 = *(const float4*)p1;
      float4 w1 = *(const float4*)(p1 + 4);
      a0[0] = (f16)(u0.x * s0); a0[1] = (f16)(u0.y * s0);
      a0[2] = (f16)(u0.z * s0); a0[3] = (f16)(u0.w * s0);
      a0[4] = (f16)(u1.x * s0); a0[5] = (f16)(u1.y * s0);
      a0[6] = (f16)(u1.z * s0); a0[7] = (f16)(u1.w * s0);
      a1[0] = (f16)(w0.x * s1); a1[1] = (f16)(w0.y * s1);
      a1[2] = (f16)(w0.z * s1); a1[3] = (f16)(w0.w * s1);
      a1[4] = (f16)(w1.x * s1); a1[5] = (f16)(w1.y * s1);
      a1[6] = (f16)(w1.z * s1); a1[7] = (f16)(w1.w * s1);
    } else {
      const f16* X = (const f16*)Xv;
      a0 = *(const f16x8*)(X + (long)ra0 * K + kbase);
      a1 = *(const f16x8*)(X + (long)ra1 * K + kbase);
    }
#pragma unroll
    for (int t = 0; t < NT; ++t) {
      f16x8 b = *(const f16x8*)(WT + (long)(t * 16 + m) * K + kbase);
      acc[0][t] =
          __builtin_amdgcn_mfma_f32_16x16x32_f16(a0, b, acc[0][t], 0, 0, 0);
      acc[1][t] =
          __builtin_amdgcn_mfma_f32_16x16x32_f16(a1, b, acc[1][t], 0, 0, 0);
    }
  }

#pragma unroll
  for (int ab = 0; ab < 2; ++ab)
#pragma unroll
    for (int r = 0; r < 4; ++r) {
      int row = wrow0 + ab * 16 + q * 4 + r;
      if (row < N_NODES) {
#pragma unroll
        for (int t = 0; t < NT; ++t)
          Mout[(long)row * NC + t * 16 + m] = (f16)acc[ab][t][r];
      }
    }
}

// ------------------------------------------------------------- gather-agg
// XCD-sharded by feature half: hf = blockIdx&1 -> with round-robin
// block->XCD dispatch, even XCDs only touch the first 128B of each M row,
// odd XCDs the second -> per-XCD compulsory L2 fetch of M halves.
// Wave = 1 dst node (its hf half); lanes in EPW groups of LPR, f16x8 loads.
__global__ __launch_bounds__(256) void gather1_kernel(
    const f16* __restrict__ M, const int* __restrict__ rowptr,
    const int* __restrict__ col, const float* __restrict__ nd,
    const float* __restrict__ ns, const float* __restrict__ b,
    f16* __restrict__ out) {
  constexpr int LPR = 8;        // 64 f16 half-row = 128 B = 8 lanes x 16 B
  constexpr int EPW = 64 / LPR; // 8 edges in parallel
  const int hf = blockIdx.x & 1;
  const int g0 = blockIdx.x >> 1;
  const int wave = threadIdx.x >> 6;
  const int lane = threadIdx.x & 63;
  const int eg = lane / LPR;
  const int t = lane % LPR;
  const int n = g0 * 4 + wave;
  if (n >= N_NODES) return;
  const int beg = rowptr[n];
  const int end = rowptr[n + 1];
  const int fo = hf * 64 + t * 8;

  float acc[8];
#pragma unroll
  for (int j = 0; j < 8; ++j) acc[j] = 0.f;

  int i = beg + eg;
  for (; i + EPW < end; i += 2 * EPW) {
    int s0 = col[i];
    int s1 = col[i + EPW];
    f16x8 v0 = *(const f16x8*)(M + (long)s0 * HIDDEN + fo);
    f16x8 v1 = *(const f16x8*)(M + (long)s1 * HIDDEN + fo);
#pragma unroll
    for (int j = 0; j < 8; ++j) acc[j] += (float)v0[j] + (float)v1[j];
  }
  if (i < end) {
    int s0 = col[i];
    f16x8 v0 = *(const f16x8*)(M + (long)s0 * HIDDEN + fo);
#pragma unroll
    for (int j = 0; j < 8; ++j) acc[j] += (float)v0[j];
  }

#pragma unroll
  for (int m2 = LPR; m2 < 64; m2 <<= 1)
#pragma unroll
    for (int j = 0; j < 8; ++j) acc[j] += __shfl_xor(acc[j], m2, 64);

  if (eg == 0) {
    float s = nd[n];
    float sn = ns[n];
    float4 bb0 = *(const float4*)(b + fo);
    float4 bb1 = *(const float4*)(b + fo + 4);
    f16x8 o;
    o[0] = (f16)(fmaxf(acc[0] * s + bb0.x, 0.f) * sn);
    o[1] = (f16)(fmaxf(acc[1] * s + bb0.y, 0.f) * sn);
    o[2] = (f16)(fmaxf(acc[2] * s + bb0.z, 0.f) * sn);
    o[3] = (f16)(fmaxf(acc[3] * s + bb0.w, 0.f) * sn);
    o[4] = (f16)(fmaxf(acc[4] * s + bb1.x, 0.f) * sn);
    o[5] = (f16)(fmaxf(acc[5] * s + bb1.y, 0.f) * sn);
    o[6] = (f16)(fmaxf(acc[6] * s + bb1.z, 0.f) * sn);
    o[7] = (f16)(fmaxf(acc[7] * s + bb1.w, 0.f) * sn);
    *(f16x8*)(out + (long)n * HIDDEN + fo) = o;
  }
}

__global__ __launch_bounds__(256) void gather2_kernel(
    const f16* __restrict__ M, const int* __restrict__ rowptr,
    const int* __restrict__ col, const float* __restrict__ nd,
    const float* __restrict__ b, float* __restrict__ out) {
  constexpr int LPR = 4;        // 32 f16 half-row = 64 B = 4 lanes x 16 B
  constexpr int EPW = 64 / LPR; // 16 edges in parallel
  const int hf = blockIdx.x & 1;
  const int g0 = blockIdx.x >> 1;
  const int wave = threadIdx.x >> 6;
  const int lane = threadIdx.x & 63;
  const int eg = lane / LPR;
  const int t = lane % LPR;
  const int n = g0 * 4 + wave;
  if (n >= N_NODES) return;
  const int beg = rowptr[n];
  const int end = rowptr[n + 1];
  const int fo = hf * 32 + t * 8;

  float acc[8];
#pragma unroll
  for (int j = 0; j < 8; ++j) acc[j] = 0.f;

  int i = beg + eg;
  for (; i + EPW < end; i += 2 * EPW) {
    int s0 = col[i];
    int s1 = col[i + EPW];
    f16x8 v0 = *(const f16x8*)(M + (long)s0 * OUT_FEATS + fo);
    f16x8 v1 = *(const f16x8*)(M + (long)s1 * OUT_FEATS + fo);
#pragma unroll
    for (int j = 0; j < 8; ++j) acc[j] += (float)v0[j] + (float)v1[j];
  }
  if (i < end) {
    int s0 = col[i];
    f16x8 v0 = *(const f16x8*)(M + (long)s0 * OUT_FEATS + fo);
#pragma unroll
    for (int j = 0; j < 8; ++j) acc[j] += (float)v0[j];
  }

#pragma unroll
  for (int m2 = LPR; m2 < 64; m2 <<= 1)
#pragma unroll
    for (int j = 0; j < 8; ++j) acc[j] += __shfl_xor(acc[j], m2, 64);

  if (eg == 0) {
    float s = nd[n];
    float4 bb0 = *(const float4*)(b + fo);
    float4 bb1 = *(const float4*)(b + fo + 4);
    float4 o0, o1;
    o0.x = acc[0] * s + bb0.x;
    o0.y = acc[1] * s + bb0.y;
    o0.z = acc[2] * s + bb0.z;
    o0.w = acc[3] * s + bb0.w;
    o1.x = acc[4] * s + bb1.x;
    o1.y = acc[5] * s + bb1.y;
    o1.z = acc[6] * s + bb1.z;
    o1.w = acc[7] * s + bb1.w;
    *(float4*)(out + (long)n * OUT_FEATS + fo) = o0;
    *(float4*)(out + (long)n * OUT_FEATS + fo + 4) = o1;
  }
}

extern "C" void kernel_launch(void* const* d_in, const int* in_sizes, int n_in,
                              void* d_out, int out_size, void* d_ws,
                              size_t ws_size, hipStream_t stream) {
  const float* x = (const float*)d_in[0];
  const int* src = (const int*)d_in[1];
  const int* dst = (const int*)d_in[2];
  const float* W1 = (const float*)d_in[3];
  const float* b1 = (const float*)d_in[4];
  const float* W2 = (const float*)d_in[5];
  const float* b2 = (const float*)d_in[6];
  float* out = (float*)d_out;

  // ---- workspace layout
  int* wi = (int*)d_ws;
  int* partial = wi;            // [256]
  int* rowptr = wi + 256;       // [50001] (pad to 50004)
  int* deg_in = wi + 50260;     // [50000]
  int* col = wi + 100260;       // [800000] -> ends at int 900260
  float* wf = (float*)d_ws + 900260;
  float* norm_src = wf;         // [50000]
  float* norm_dst = wf + 50000; // [50000]
  f16* fh = (f16*)(wf + 100000);
  f16* W1T = fh;                // [128*256]
  f16* W2T = fh + 128 * 256;    // [64*128]
  f16* m1 = fh + 128 * 256 + 64 * 128;  // [50048*128]
  f16* h1p = m1 + (long)50048 * 128;    // [50048*128]
  f16* m2 = h1p + (long)50048 * 128;    // [50048*64]

  // hist overlay on m1/h1p/m2 region: 2 arrays * 64 chunks * 65536 u16
  // = 16.8 MB < 32 MB region; dead before gemm1 writes m1 (stream-ordered).
  unsigned* hist_src = (unsigned*)m1;                       // u16[NCHUNK*NBT]
  unsigned* hist_dst = hist_src + (long)NCHUNK * NBT / 2;   // u16[NCHUNK*NBT]

  const int nb_nodes = (N_NODES + 255) / 256;  // 196

  // ---- degrees + norms + CSR (no global atomics)
  hist_kernel<<<NRANGE * NCHUNK, 256, 0, stream>>>(src, dst, hist_src,
                                                   hist_dst);
  reduce_kernel<<<nb_nodes, 256, 0, stream>>>(hist_src, hist_dst, deg_in,
                                              norm_src, norm_dst, partial);
  scan2<<<1, 256, 0, stream>>>(partial, nb_nodes);
  scan3<<<nb_nodes, 256, 0, stream>>>(deg_in, partial, rowptr);
  fill_csr<<<NRANGE * NCHUNK, 256, 0, stream>>>(src, dst, rowptr, hist_dst,
                                                col);
  wtrans<<<(128 * 256 + 64 * 128 + 255) / 256, 256, 0, stream>>>(W1, W2, W1T,
                                                                 W2T);

  // ---- layer 1
  gemm_mfma<IN_FEATS, HIDDEN, true>
      <<<(N_NODES + 127) / 128, 256, 0, stream>>>(x, W1T, norm_src, m1);
  gather1_kernel<<<2 * ((N_NODES + 3) / 4), 256, 0, stream>>>(
      m1, rowptr, col, norm_dst, norm_src, b1, h1p);

  // ---- layer 2
  gemm_mfma<HIDDEN, OUT_FEATS, false>
      <<<(N_NODES + 127) / 128, 256, 0, stream>>>(h1p, W2T, norm_src, m2);
  gather2_kernel<<<2 * ((N_NODES + 3) / 4), 256, 0, stream>>>(
      m2, rowptr, col, norm_dst, b2, out);
}

// Round 9
// 251.607 us; speedup vs baseline: 1.1151x; 1.1151x over previous
//
#include <hip/hip_runtime.h>

#define N_NODES 50000
#define N_EDGES 800000
#define IN_FEATS 256
#define HIDDEN 128
#define OUT_FEATS 64

// ---- LDS-histogram decomposition (packed u16 counters) ----
#define NB 16384             // bins per range (2 bins/u32 word -> 32 KB LDS)
#define NRANGE 4             // ceil(50000/16384)
#define NBT (NRANGE * NB)    // 65536 padded bins per copy (u16 each)
#define NCHUNK 64            // edge chunks (= privatized copies)
#define EPC 12500            // edges per chunk; per-bin count <= 12500 < 2^16

typedef _Float16 f16;
typedef _Float16 f16x8 __attribute__((ext_vector_type(8)));
typedef float f32x4 __attribute__((ext_vector_type(4)));

// ---------------------------------------------------------- LDS histogram
// Zero global atomics (gfx950 global atomics cost ~32B beyond-L2 traffic
// each regardless of locality — measured R3/R4). u16 counters packed two
// per u32; no cross-half carry since per-chunk bin count <= EPC=12500.
__global__ __launch_bounds__(256) void hist_kernel(
    const int* __restrict__ src, const int* __restrict__ dst,
    unsigned* __restrict__ hist_src, unsigned* __restrict__ hist_dst) {
  __shared__ unsigned ls[NB / 2];   // 32 KB
  __shared__ unsigned ld2[NB / 2];  // 32 KB
  const int r = blockIdx.x % NRANGE;
  const int c = blockIdx.x / NRANGE;
  const int lo = r * NB;
  for (int i = threadIdx.x; i < NB / 2; i += 256) {
    ls[i] = 0;
    ld2[i] = 0;
  }
  __syncthreads();
  const int4* s4 = (const int4*)(src + c * EPC);
  const int4* d4 = (const int4*)(dst + c * EPC);
  for (int i = threadIdx.x; i < EPC / 4; i += 256) {
    int4 s = s4[i];
    int4 d = d4[i];
    unsigned b;
    b = (unsigned)(s.x - lo); if (b < NB) atomicAdd(&ls[b >> 1], 1u << ((b & 1) << 4));
    b = (unsigned)(s.y - lo); if (b < NB) atomicAdd(&ls[b >> 1], 1u << ((b & 1) << 4));
    b = (unsigned)(s.z - lo); if (b < NB) atomicAdd(&ls[b >> 1], 1u << ((b & 1) << 4));
    b = (unsigned)(s.w - lo); if (b < NB) atomicAdd(&ls[b >> 1], 1u << ((b & 1) << 4));
    b = (unsigned)(d.x - lo); if (b < NB) atomicAdd(&ld2[b >> 1], 1u << ((b & 1) << 4));
    b = (unsigned)(d.y - lo); if (b < NB) atomicAdd(&ld2[b >> 1], 1u << ((b & 1) << 4));
    b = (unsigned)(d.z - lo); if (b < NB) atomicAdd(&ld2[b >> 1], 1u << ((b & 1) << 4));
    b = (unsigned)(d.w - lo); if (b < NB) atomicAdd(&ld2[b >> 1], 1u << ((b & 1) << 4));
  }
  __syncthreads();
  unsigned* hs = hist_src + ((long)c * NBT + lo) / 2;
  unsigned* hd = hist_dst + ((long)c * NBT + lo) / 2;
  for (int i = threadIdx.x; i < NB / 2; i += 256) {
    hs[i] = ls[i];
    hd[i] = ld2[i];
  }
}

// sum copies -> norms; hist_dst -> exclusive prefix over copies (u16; max
// in-degree ~50 << 2^16); emits per-block degree sums (folded scan1).
__global__ __launch_bounds__(256) void reduce_kernel(
    const unsigned* __restrict__ hist_src, unsigned* __restrict__ hist_dst,
    int* __restrict__ deg_in, float* __restrict__ norm_src,
    float* __restrict__ norm_dst, int* __restrict__ partial) {
  const unsigned short* hs = (const unsigned short*)hist_src;
  unsigned short* hd = (unsigned short*)hist_dst;
  int n = blockIdx.x * 256 + threadIdx.x;
  int run = 0;
  if (n < N_NODES) {
    int so = 0;
#pragma unroll 8
    for (int c = 0; c < NCHUNK; ++c) so += hs[(long)c * NBT + n];
    norm_src[n] = rsqrtf((float)max(so, 1));
#pragma unroll 8
    for (int c = 0; c < NCHUNK; ++c) {
      int t = hd[(long)c * NBT + n];
      hd[(long)c * NBT + n] = (unsigned short)run;
      run += t;
    }
    deg_in[n] = run;
    norm_dst[n] = rsqrtf((float)max(run, 1));
  }
  __shared__ int sd[256];
  sd[threadIdx.x] = run;
  __syncthreads();
  for (int s = 128; s > 0; s >>= 1) {
    if (threadIdx.x < s) sd[threadIdx.x] += sd[threadIdx.x + s];
    __syncthreads();
  }
  if (threadIdx.x == 0) partial[blockIdx.x] = sd[0];
}

// ------------------------------------------------------------- prefix scan
__global__ __launch_bounds__(256) void scan2(int* __restrict__ partial,
                                             int nb) {
  __shared__ int sd[256];
  int v = (threadIdx.x < nb) ? partial[threadIdx.x] : 0;
  sd[threadIdx.x] = v;
  __syncthreads();
  for (int off = 1; off < 256; off <<= 1) {
    int t = sd[threadIdx.x] +
            ((threadIdx.x >= off) ? sd[threadIdx.x - off] : 0);
    __syncthreads();
    sd[threadIdx.x] = t;
    __syncthreads();
  }
  if (threadIdx.x < nb) partial[threadIdx.x] = sd[threadIdx.x] - v;  // excl
}

__global__ __launch_bounds__(256) void scan3(const int* __restrict__ deg,
                                             const int* __restrict__ partial,
                                             int* __restrict__ rowptr) {
  __shared__ int sd[256];
  int i = blockIdx.x * 256 + threadIdx.x;
  int v = (i < N_NODES) ? deg[i] : 0;
  sd[threadIdx.x] = v;
  __syncthreads();
  for (int off = 1; off < 256; off <<= 1) {
    int t = sd[threadIdx.x] +
            ((threadIdx.x >= off) ? sd[threadIdx.x - off] : 0);
    __syncthreads();
    sd[threadIdx.x] = t;
    __syncthreads();
  }
  if (i < N_NODES) rowptr[i] = partial[blockIdx.x] + sd[threadIdx.x] - v;
  if (blockIdx.x == 0 && threadIdx.x == 0) rowptr[N_NODES] = N_EDGES;
}

// ------------------------------------------------------------- CSR fill
__global__ __launch_bounds__(256) void fill_csr(
    const int* __restrict__ src, const int* __restrict__ dst,
    const int* __restrict__ rowptr, const unsigned* __restrict__ pref32,
    int* __restrict__ col) {
  __shared__ int cur[NB];  // 64 KB
  const unsigned short* pref = (const unsigned short*)pref32;
  const int r = blockIdx.x % NRANGE;
  const int c = blockIdx.x / NRANGE;
  const int lo = r * NB;
  for (int i = threadIdx.x; i < NB; i += 256) {
    int n = lo + i;
    cur[i] = (n < N_NODES) ? rowptr[n] + pref[(long)c * NBT + n] : 0;
  }
  __syncthreads();
  const int4* s4 = (const int4*)(src + c * EPC);
  const int4* d4 = (const int4*)(dst + c * EPC);
  for (int i = threadIdx.x; i < EPC / 4; i += 256) {
    int4 s = s4[i];
    int4 d = d4[i];
    unsigned b;
    b = (unsigned)(d.x - lo);
    if (b < NB) col[atomicAdd(&cur[b], 1)] = s.x;
    b = (unsigned)(d.y - lo);
    if (b < NB) col[atomicAdd(&cur[b], 1)] = s.y;
    b = (unsigned)(d.z - lo);
    if (b < NB) col[atomicAdd(&cur[b], 1)] = s.z;
    b = (unsigned)(d.w - lo);
    if (b < NB) col[atomicAdd(&cur[b], 1)] = s.w;
  }
}

// ------------------------------------------------------------- W transpose
__global__ __launch_bounds__(256) void wtrans(const float* __restrict__ W1,
                                              const float* __restrict__ W2,
                                              f16* __restrict__ W1T,
                                              f16* __restrict__ W2T) {
  int i = blockIdx.x * 256 + threadIdx.x;
  if (i < 128 * 256) {
    int n = i >> 8, k = i & 255;
    W1T[i] = (f16)W1[k * 128 + n];
  } else if (i < 128 * 256 + 64 * 128) {
    int j = i - 128 * 256;
    int n = j >> 7, k = j & 127;
    W2T[j] = (f16)W2[k * 64 + n];
  }
}

// ------------------------------------------------------------- MFMA GEMM
template <int K, int NC, bool FP32IN>
__global__ __launch_bounds__(256) void gemm_mfma(
    const void* __restrict__ Xv, const f16* __restrict__ WT,
    const float* __restrict__ ns, f16* __restrict__ Mout) {
  constexpr int KI = K / 32;
  constexpr int NT = NC / 16;
  const int wave = threadIdx.x >> 6;
  const int lane = threadIdx.x & 63;
  const int m = lane & 15;
  const int q = lane >> 4;
  const int wrow0 = blockIdx.x * 128 + wave * 32;

  const int ra0 = min(wrow0 + m, N_NODES - 1);
  const int ra1 = min(wrow0 + 16 + m, N_NODES - 1);
  const float s0 = FP32IN ? ns[ra0] : 0.f;
  const float s1 = FP32IN ? ns[ra1] : 0.f;

  f32x4 acc[2][NT];
#pragma unroll
  for (int ab = 0; ab < 2; ++ab)
#pragma unroll
    for (int t = 0; t < NT; ++t) acc[ab][t] = (f32x4){0.f, 0.f, 0.f, 0.f};

#pragma unroll
  for (int ki = 0; ki < KI; ++ki) {
    const int kbase = ki * 32 + q * 8;
    f16x8 a0, a1;
    if (FP32IN) {
      const float* X = (const float*)Xv;
      const float* p0 = X + (long)ra0 * K + kbase;
      const float* p1 = X + (long)ra1 * K + kbase;
      float4 u0 = *(const float4*)p0;
      float4 u1 = *(const float4*)(p0 + 4);
      float4 w0 = *(const float4*)p1;
      float4 w1 = *(const float4*)(p1 + 4);
      a0[0] = (f16)(u0.x * s0); a0[1] = (f16)(u0.y * s0);
      a0[2] = (f16)(u0.z * s0); a0[3] = (f16)(u0.w * s0);
      a0[4] = (f16)(u1.x * s0); a0[5] = (f16)(u1.y * s0);
      a0[6] = (f16)(u1.z * s0); a0[7] = (f16)(u1.w * s0);
      a1[0] = (f16)(w0.x * s1); a1[1] = (f16)(w0.y * s1);
      a1[2] = (f16)(w0.z * s1); a1[3] = (f16)(w0.w * s1);
      a1[4] = (f16)(w1.x * s1); a1[5] = (f16)(w1.y * s1);
      a1[6] = (f16)(w1.z * s1); a1[7] = (f16)(w1.w * s1);
    } else {
      const f16* X = (const f16*)Xv;
      a0 = *(const f16x8*)(X + (long)ra0 * K + kbase);
      a1 = *(const f16x8*)(X + (long)ra1 * K + kbase);
    }
#pragma unroll
    for (int t = 0; t < NT; ++t) {
      f16x8 b = *(const f16x8*)(WT + (long)(t * 16 + m) * K + kbase);
      acc[0][t] =
          __builtin_amdgcn_mfma_f32_16x16x32_f16(a0, b, acc[0][t], 0, 0, 0);
      acc[1][t] =
          __builtin_amdgcn_mfma_f32_16x16x32_f16(a1, b, acc[1][t], 0, 0, 0);
    }
  }

#pragma unroll
  for (int ab = 0; ab < 2; ++ab)
#pragma unroll
    for (int r = 0; r < 4; ++r) {
      int row = wrow0 + ab * 16 + q * 4 + r;
      if (row < N_NODES) {
#pragma unroll
        for (int t = 0; t < NT; ++t)
          Mout[(long)row * NC + t * 16 + m] = (f16)acc[ab][t][r];
      }
    }
}

// ------------------------------------------------------------- gather-agg
// Wave = 1 dst node. Per 64-edge window: ONE coalesced col load; groups get
// edge indices via __shfl. CRITICAL: the per-window loop trip count is
// WAVE-UNIFORM (ntrip = ceil(cnt/GROUPS)) so every lane executes every
// __shfl — ds_bpermute returns garbage when the SOURCE lane's EXEC bit is
// 0 (R7 failure: divergent group exit corrupted tail-window edges). Only
// the row load/accumulate is predicated on e < cnt.
__global__ __launch_bounds__(256) void gather1_kernel(
    const f16* __restrict__ M, const int* __restrict__ rowptr,
    const int* __restrict__ col, const float* __restrict__ nd,
    const float* __restrict__ ns, const float* __restrict__ b,
    f16* __restrict__ out) {
  const int wave = threadIdx.x >> 6;
  const int lane = threadIdx.x & 63;
  const int g = lane >> 4;   // 4 groups of 16 lanes
  const int t = lane & 15;   // 16 lanes x 16 B = 256 B full row
  const int n = blockIdx.x * 4 + wave;
  if (n >= N_NODES) return;
  const int beg = rowptr[n];
  const int end = rowptr[n + 1];

  float acc[8];
#pragma unroll
  for (int j = 0; j < 8; ++j) acc[j] = 0.f;

  for (int base = beg; base < end; base += 64) {
    const int cnt = min(64, end - base);        // wave-uniform
    const int ntrip = (cnt + 3) >> 2;           // wave-uniform trips
    int myc = (lane < cnt) ? col[base + lane] : 0;
#pragma unroll 2
    for (int k = 0; k < ntrip; ++k) {
      int e = g + 4 * k;                        // e <= 3 + 4*15 = 63
      int sidx = __shfl(myc, e, 64);            // all 64 lanes active
      if (e < cnt) {
        f16x8 v = *(const f16x8*)(M + (long)sidx * HIDDEN + t * 8);
#pragma unroll
        for (int j = 0; j < 8; ++j) acc[j] += (float)v[j];
      }
    }
  }

#pragma unroll
  for (int m2 = 16; m2 < 64; m2 <<= 1)
#pragma unroll
    for (int j = 0; j < 8; ++j) acc[j] += __shfl_xor(acc[j], m2, 64);

  if (g == 0) {
    float s = nd[n];
    float sn = ns[n];
    float4 bb0 = *(const float4*)(b + t * 8);
    float4 bb1 = *(const float4*)(b + t * 8 + 4);
    f16x8 o;
    o[0] = (f16)(fmaxf(acc[0] * s + bb0.x, 0.f) * sn);
    o[1] = (f16)(fmaxf(acc[1] * s + bb0.y, 0.f) * sn);
    o[2] = (f16)(fmaxf(acc[2] * s + bb0.z, 0.f) * sn);
    o[3] = (f16)(fmaxf(acc[3] * s + bb0.w, 0.f) * sn);
    o[4] = (f16)(fmaxf(acc[4] * s + bb1.x, 0.f) * sn);
    o[5] = (f16)(fmaxf(acc[5] * s + bb1.y, 0.f) * sn);
    o[6] = (f16)(fmaxf(acc[6] * s + bb1.z, 0.f) * sn);
    o[7] = (f16)(fmaxf(acc[7] * s + bb1.w, 0.f) * sn);
    *(f16x8*)(out + (long)n * HIDDEN + t * 8) = o;
  }
}

__global__ __launch_bounds__(256) void gather2_kernel(
    const f16* __restrict__ M, const int* __restrict__ rowptr,
    const int* __restrict__ col, const float* __restrict__ nd,
    const float* __restrict__ b, float* __restrict__ out) {
  const int wave = threadIdx.x >> 6;
  const int lane = threadIdx.x & 63;
  const int g = lane >> 3;   // 8 groups of 8 lanes
  const int t = lane & 7;    // 8 lanes x 16 B = 128 B full row
  const int n = blockIdx.x * 4 + wave;
  if (n >= N_NODES) return;
  const int beg = rowptr[n];
  const int end = rowptr[n + 1];

  float acc[8];
#pragma unroll
  for (int j = 0; j < 8; ++j) acc[j] = 0.f;

  for (int base = beg; base < end; base += 64) {
    const int cnt = min(64, end - base);        // wave-uniform
    const int ntrip = (cnt + 7) >> 3;           // wave-uniform trips
    int myc = (lane < cnt) ? col[base + lane] : 0;
#pragma unroll 2
    for (int k = 0; k < ntrip; ++k) {
      int e = g + 8 * k;                        // e <= 7 + 8*7 = 63
      int sidx = __shfl(myc, e, 64);            // all 64 lanes active
      if (e < cnt) {
        f16x8 v = *(const f16x8*)(M + (long)sidx * OUT_FEATS + t * 8);
#pragma unroll
        for (int j = 0; j < 8; ++j) acc[j] += (float)v[j];
      }
    }
  }

#pragma unroll
  for (int m2 = 8; m2 < 64; m2 <<= 1)
#pragma unroll
    for (int j = 0; j < 8; ++j) acc[j] += __shfl_xor(acc[j], m2, 64);

  if (g == 0) {
    float s = nd[n];
    float4 bb0 = *(const float4*)(b + t * 8);
    float4 bb1 = *(const float4*)(b + t * 8 + 4);
    float4 o0, o1;
    o0.x = acc[0] * s + bb0.x;
    o0.y = acc[1] * s + bb0.y;
    o0.z = acc[2] * s + bb0.z;
    o0.w = acc[3] * s + bb0.w;
    o1.x = acc[4] * s + bb1.x;
    o1.y = acc[5] * s + bb1.y;
    o1.z = acc[6] * s + bb1.z;
    o1.w = acc[7] * s + bb1.w;
    *(float4*)(out + (long)n * OUT_FEATS + t * 8) = o0;
    *(float4*)(out + (long)n * OUT_FEATS + t * 8 + 4) = o1;
  }
}

extern "C" void kernel_launch(void* const* d_in, const int* in_sizes, int n_in,
                              void* d_out, int out_size, void* d_ws,
                              size_t ws_size, hipStream_t stream) {
  const float* x = (const float*)d_in[0];
  const int* src = (const int*)d_in[1];
  const int* dst = (const int*)d_in[2];
  const float* W1 = (const float*)d_in[3];
  const float* b1 = (const float*)d_in[4];
  const float* W2 = (const float*)d_in[5];
  const float* b2 = (const float*)d_in[6];
  float* out = (float*)d_out;

  // ---- workspace layout
  int* wi = (int*)d_ws;
  int* partial = wi;            // [256]
  int* rowptr = wi + 256;       // [50001] (pad to 50004)
  int* deg_in = wi + 50260;     // [50000]
  int* col = wi + 100260;       // [800000] -> ends at int 900260
  float* wf = (float*)d_ws + 900260;
  float* norm_src = wf;         // [50000]
  float* norm_dst = wf + 50000; // [50000]
  f16* fh = (f16*)(wf + 100000);
  f16* W1T = fh;                // [128*256]
  f16* W2T = fh + 128 * 256;    // [64*128]
  f16* m1 = fh + 128 * 256 + 64 * 128;  // [50048*128]
  f16* h1p = m1 + (long)50048 * 128;    // [50048*128]
  f16* m2 = h1p + (long)50048 * 128;    // [50048*64]

  // hist overlay on m1/h1p/m2 region: 16.8 MB < 32 MB region; dead before
  // gemm1 writes m1 (stream-ordered).
  unsigned* hist_src = (unsigned*)m1;                       // u16[NCHUNK*NBT]
  unsigned* hist_dst = hist_src + (long)NCHUNK * NBT / 2;   // u16[NCHUNK*NBT]

  const int nb_nodes = (N_NODES + 255) / 256;  // 196

  // ---- degrees + norms + CSR (no global atomics)
  hist_kernel<<<NRANGE * NCHUNK, 256, 0, stream>>>(src, dst, hist_src,
                                                   hist_dst);
  reduce_kernel<<<nb_nodes, 256, 0, stream>>>(hist_src, hist_dst, deg_in,
                                              norm_src, norm_dst, partial);
  scan2<<<1, 256, 0, stream>>>(partial, nb_nodes);
  scan3<<<nb_nodes, 256, 0, stream>>>(deg_in, partial, rowptr);
  fill_csr<<<NRANGE * NCHUNK, 256, 0, stream>>>(src, dst, rowptr, hist_dst,
                                                col);
  wtrans<<<(128 * 256 + 64 * 128 + 255) / 256, 256, 0, stream>>>(W1, W2, W1T,
                                                                 W2T);

  // ---- layer 1
  gemm_mfma<IN_FEATS, HIDDEN, true>
      <<<(N_NODES + 127) / 128, 256, 0, stream>>>(x, W1T, norm_src, m1);
  gather1_kernel<<<(N_NODES + 3) / 4, 256, 0, stream>>>(m1, rowptr, col,
                                                        norm_dst, norm_src, b1,
                                                        h1p);

  // ---- layer 2
  gemm_mfma<HIDDEN, OUT_FEATS, false>
      <<<(N_NODES + 127) / 128, 256, 0, stream>>>(h1p, W2T, norm_src, m2);
  gather2_kernel<<<(N_NODES + 3) / 4, 256, 0, stream>>>(m2, rowptr, col,
                                                        norm_dst, b2, out);
}

// Round 10
// 241.463 us; speedup vs baseline: 1.1619x; 1.0420x over previous
//
#include <hip/hip_runtime.h>

#define N_NODES 50000
#define N_EDGES 800000
#define IN_FEATS 256
#define HIDDEN 128
#define OUT_FEATS 64

// ---- LDS-histogram decomposition (packed u16 counters) ----
#define NB 16384             // bins per range (2 bins/u32 word -> 32 KB LDS)
#define NRANGE 4             // ceil(50000/16384)
#define NBT (NRANGE * NB)    // 65536 padded bins per copy (u16 each)
#define NCHUNK 64            // edge chunks (= privatized copies)
#define EPC 12500            // edges per chunk; per-bin count <= 12500 < 2^16

typedef _Float16 f16;
typedef _Float16 f16x8 __attribute__((ext_vector_type(8)));
typedef float f32x4 __attribute__((ext_vector_type(4)));

// ---------------------------------------------------------- LDS histogram
// Zero global atomics (gfx950 global atomics cost ~32B beyond-L2 traffic
// each regardless of locality — measured R3/R4). u16 counters packed two
// per u32; no cross-half carry since per-chunk bin count <= EPC=12500.
__global__ __launch_bounds__(256) void hist_kernel(
    const int* __restrict__ src, const int* __restrict__ dst,
    unsigned* __restrict__ hist_src, unsigned* __restrict__ hist_dst) {
  __shared__ unsigned ls[NB / 2];   // 32 KB
  __shared__ unsigned ld2[NB / 2];  // 32 KB
  const int r = blockIdx.x % NRANGE;
  const int c = blockIdx.x / NRANGE;
  const int lo = r * NB;
  for (int i = threadIdx.x; i < NB / 2; i += 256) {
    ls[i] = 0;
    ld2[i] = 0;
  }
  __syncthreads();
  const int4* s4 = (const int4*)(src + c * EPC);
  const int4* d4 = (const int4*)(dst + c * EPC);
  for (int i = threadIdx.x; i < EPC / 4; i += 256) {
    int4 s = s4[i];
    int4 d = d4[i];
    unsigned b;
    b = (unsigned)(s.x - lo); if (b < NB) atomicAdd(&ls[b >> 1], 1u << ((b & 1) << 4));
    b = (unsigned)(s.y - lo); if (b < NB) atomicAdd(&ls[b >> 1], 1u << ((b & 1) << 4));
    b = (unsigned)(s.z - lo); if (b < NB) atomicAdd(&ls[b >> 1], 1u << ((b & 1) << 4));
    b = (unsigned)(s.w - lo); if (b < NB) atomicAdd(&ls[b >> 1], 1u << ((b & 1) << 4));
    b = (unsigned)(d.x - lo); if (b < NB) atomicAdd(&ld2[b >> 1], 1u << ((b & 1) << 4));
    b = (unsigned)(d.y - lo); if (b < NB) atomicAdd(&ld2[b >> 1], 1u << ((b & 1) << 4));
    b = (unsigned)(d.z - lo); if (b < NB) atomicAdd(&ld2[b >> 1], 1u << ((b & 1) << 4));
    b = (unsigned)(d.w - lo); if (b < NB) atomicAdd(&ld2[b >> 1], 1u << ((b & 1) << 4));
  }
  __syncthreads();
  unsigned* hs = hist_src + ((long)c * NBT + lo) / 2;
  unsigned* hd = hist_dst + ((long)c * NBT + lo) / 2;
  for (int i = threadIdx.x; i < NB / 2; i += 256) {
    hs[i] = ls[i];
    hd[i] = ld2[i];
  }
}

// sum copies -> norms; hist_dst -> exclusive prefix over copies (u16; max
// in-degree ~50 << 2^16); emits per-block degree sums (folded scan1).
__global__ __launch_bounds__(256) void reduce_kernel(
    const unsigned* __restrict__ hist_src, unsigned* __restrict__ hist_dst,
    int* __restrict__ deg_in, float* __restrict__ norm_src,
    float* __restrict__ norm_dst, int* __restrict__ partial) {
  const unsigned short* hs = (const unsigned short*)hist_src;
  unsigned short* hd = (unsigned short*)hist_dst;
  int n = blockIdx.x * 256 + threadIdx.x;
  int run = 0;
  if (n < N_NODES) {
    int so = 0;
#pragma unroll 8
    for (int c = 0; c < NCHUNK; ++c) so += hs[(long)c * NBT + n];
    norm_src[n] = rsqrtf((float)max(so, 1));
#pragma unroll 8
    for (int c = 0; c < NCHUNK; ++c) {
      int t = hd[(long)c * NBT + n];
      hd[(long)c * NBT + n] = (unsigned short)run;
      run += t;
    }
    deg_in[n] = run;
    norm_dst[n] = rsqrtf((float)max(run, 1));
  }
  __shared__ int sd[256];
  sd[threadIdx.x] = run;
  __syncthreads();
  for (int s = 128; s > 0; s >>= 1) {
    if (threadIdx.x < s) sd[threadIdx.x] += sd[threadIdx.x + s];
    __syncthreads();
  }
  if (threadIdx.x == 0) partial[blockIdx.x] = sd[0];
}

// ------------------------------------------------------------- prefix scan
__global__ __launch_bounds__(256) void scan2(int* __restrict__ partial,
                                             int nb) {
  __shared__ int sd[256];
  int v = (threadIdx.x < nb) ? partial[threadIdx.x] : 0;
  sd[threadIdx.x] = v;
  __syncthreads();
  for (int off = 1; off < 256; off <<= 1) {
    int t = sd[threadIdx.x] +
            ((threadIdx.x >= off) ? sd[threadIdx.x - off] : 0);
    __syncthreads();
    sd[threadIdx.x] = t;
    __syncthreads();
  }
  if (threadIdx.x < nb) partial[threadIdx.x] = sd[threadIdx.x] - v;  // excl
}

__global__ __launch_bounds__(256) void scan3(const int* __restrict__ deg,
                                             const int* __restrict__ partial,
                                             int* __restrict__ rowptr) {
  __shared__ int sd[256];
  int i = blockIdx.x * 256 + threadIdx.x;
  int v = (i < N_NODES) ? deg[i] : 0;
  sd[threadIdx.x] = v;
  __syncthreads();
  for (int off = 1; off < 256; off <<= 1) {
    int t = sd[threadIdx.x] +
            ((threadIdx.x >= off) ? sd[threadIdx.x - off] : 0);
    __syncthreads();
    sd[threadIdx.x] = t;
    __syncthreads();
  }
  if (i < N_NODES) rowptr[i] = partial[blockIdx.x] + sd[threadIdx.x] - v;
  if (blockIdx.x == 0 && threadIdx.x == 0) rowptr[N_NODES] = N_EDGES;
}

// ------------------------------------------------------------- CSR fill
__global__ __launch_bounds__(256) void fill_csr(
    const int* __restrict__ src, const int* __restrict__ dst,
    const int* __restrict__ rowptr, const unsigned* __restrict__ pref32,
    int* __restrict__ col) {
  __shared__ int cur[NB];  // 64 KB
  const unsigned short* pref = (const unsigned short*)pref32;
  const int r = blockIdx.x % NRANGE;
  const int c = blockIdx.x / NRANGE;
  const int lo = r * NB;
  for (int i = threadIdx.x; i < NB; i += 256) {
    int n = lo + i;
    cur[i] = (n < N_NODES) ? rowptr[n] + pref[(long)c * NBT + n] : 0;
  }
  __syncthreads();
  const int4* s4 = (const int4*)(src + c * EPC);
  const int4* d4 = (const int4*)(dst + c * EPC);
  for (int i = threadIdx.x; i < EPC / 4; i += 256) {
    int4 s = s4[i];
    int4 d = d4[i];
    unsigned b;
    b = (unsigned)(d.x - lo);
    if (b < NB) col[atomicAdd(&cur[b], 1)] = s.x;
    b = (unsigned)(d.y - lo);
    if (b < NB) col[atomicAdd(&cur[b], 1)] = s.y;
    b = (unsigned)(d.z - lo);
    if (b < NB) col[atomicAdd(&cur[b], 1)] = s.z;
    b = (unsigned)(d.w - lo);
    if (b < NB) col[atomicAdd(&cur[b], 1)] = s.w;
  }
}

// ------------------------------------------------------------- W transpose
__global__ __launch_bounds__(256) void wtrans(const float* __restrict__ W1,
                                              const float* __restrict__ W2,
                                              f16* __restrict__ W1T,
                                              f16* __restrict__ W2T) {
  int i = blockIdx.x * 256 + threadIdx.x;
  if (i < 128 * 256) {
    int n = i >> 8, k = i & 255;
    W1T[i] = (f16)W1[k * 128 + n];
  } else if (i < 128 * 256 + 64 * 128) {
    int j = i - 128 * 256;
    int n = j >> 7, k = j & 127;
    W2T[j] = (f16)W2[k * 64 + n];
  }
}

// ------------------------------------------------------------- MFMA GEMM
// Occupancy-first redesign (R9: old 128-row blocks gave only 1.5 waves/SIMD
// — grid-starved latency hiding). Block = 4 waves x 16 rows = 64 rows,
// TN*16 = 64 cols; W-tile staged once per block into LDS (row pad +8 f16
// -> 2-way bank pattern, free per m136); B-frags via ds_read_b128.
// gemm1: grid 1564 (~4 waves/SIMD, LDS 33.8KB -> 4 blocks/CU);
// gemm2: grid 782 (~3 waves/SIMD).
template <int K, int NC, int TN, bool FP32IN>
__global__ __launch_bounds__(256) void gemm_mfma(
    const void* __restrict__ Xv, const f16* __restrict__ WT,
    const float* __restrict__ ns, f16* __restrict__ Mout) {
  constexpr int KI = K / 32;
  constexpr int COLBLK = NC / (TN * 16);
  constexpr int KP = K + 8;  // padded LDS row stride (f16)
  __shared__ f16 Bs[TN * 16 * KP];

  const int cb = blockIdx.x % COLBLK;
  const int rb = blockIdx.x / COLBLK;
  const int col0 = cb * TN * 16;
  const int wave = threadIdx.x >> 6;
  const int lane = threadIdx.x & 63;
  const int m = lane & 15;
  const int q = lane >> 4;
  const int row0 = rb * 64 + wave * 16;

  // stage W tile: TN*16 rows of K f16 (contiguous in WT from col0*K)
  for (int idx = threadIdx.x; idx < TN * 16 * (K / 8); idx += 256) {
    int n = idx / (K / 8);
    int kk = idx % (K / 8);
    *(f16x8*)(Bs + n * KP + kk * 8) =
        *(const f16x8*)(WT + (long)(col0 + n) * K + kk * 8);
  }
  __syncthreads();

  const int ra = min(row0 + m, N_NODES - 1);
  const float s = FP32IN ? ns[ra] : 0.f;

  f32x4 acc[TN];
#pragma unroll
  for (int t = 0; t < TN; ++t) acc[t] = (f32x4){0.f, 0.f, 0.f, 0.f};

#pragma unroll
  for (int ki = 0; ki < KI; ++ki) {
    const int kb = ki * 32 + q * 8;
    f16x8 a;
    if (FP32IN) {
      const float* X = (const float*)Xv;
      const float* p = X + (long)ra * K + kb;
      float4 u0 = *(const float4*)p;
      float4 u1 = *(const float4*)(p + 4);
      a[0] = (f16)(u0.x * s); a[1] = (f16)(u0.y * s);
      a[2] = (f16)(u0.z * s); a[3] = (f16)(u0.w * s);
      a[4] = (f16)(u1.x * s); a[5] = (f16)(u1.y * s);
      a[6] = (f16)(u1.z * s); a[7] = (f16)(u1.w * s);
    } else {
      const f16* X = (const f16*)Xv;
      a = *(const f16x8*)(X + (long)ra * K + kb);
    }
#pragma unroll
    for (int t = 0; t < TN; ++t) {
      f16x8 b = *(const f16x8*)(Bs + (t * 16 + m) * KP + kb);
      acc[t] = __builtin_amdgcn_mfma_f32_16x16x32_f16(a, b, acc[t], 0, 0, 0);
    }
  }

#pragma unroll
  for (int r = 0; r < 4; ++r) {
    int row = row0 + q * 4 + r;
    if (row < N_NODES) {
#pragma unroll
      for (int t = 0; t < TN; ++t)
        Mout[(long)row * NC + col0 + t * 16 + m] = (f16)acc[t][r];
    }
  }
}

// ------------------------------------------------------------- gather-agg
// R6 measured-best form: wave = 1 dst node, full rows, EPW groups of LPR
// lanes, f16x8 (16 B/lane), group-stride + unroll 2. (Shuffle variant R9
// was neutral-to-worse — gather is at its L2/L3 random-row floor.)
__global__ __launch_bounds__(256) void gather1_kernel(
    const f16* __restrict__ M, const int* __restrict__ rowptr,
    const int* __restrict__ col, const float* __restrict__ nd,
    const float* __restrict__ ns, const float* __restrict__ b,
    f16* __restrict__ out) {
  constexpr int LPR = 16;       // 128 f16 = 256 B row / 16 B per lane
  constexpr int EPW = 64 / LPR; // 4 edges in parallel
  const int wave = threadIdx.x >> 6;
  const int lane = threadIdx.x & 63;
  const int eg = lane / LPR;
  const int t = lane % LPR;
  const int n = blockIdx.x * 4 + wave;
  if (n >= N_NODES) return;
  const int beg = rowptr[n];
  const int end = rowptr[n + 1];

  float acc[8];
#pragma unroll
  for (int j = 0; j < 8; ++j) acc[j] = 0.f;

  int i = beg + eg;
  for (; i + EPW < end; i += 2 * EPW) {
    int s0 = col[i];
    int s1 = col[i + EPW];
    f16x8 v0 = *(const f16x8*)(M + (long)s0 * HIDDEN + t * 8);
    f16x8 v1 = *(const f16x8*)(M + (long)s1 * HIDDEN + t * 8);
#pragma unroll
    for (int j = 0; j < 8; ++j) acc[j] += (float)v0[j] + (float)v1[j];
  }
  if (i < end) {
    int s0 = col[i];
    f16x8 v0 = *(const f16x8*)(M + (long)s0 * HIDDEN + t * 8);
#pragma unroll
    for (int j = 0; j < 8; ++j) acc[j] += (float)v0[j];
  }

#pragma unroll
  for (int m2 = LPR; m2 < 64; m2 <<= 1)
#pragma unroll
    for (int j = 0; j < 8; ++j) acc[j] += __shfl_xor(acc[j], m2, 64);

  if (eg == 0) {
    float s = nd[n];
    float sn = ns[n];
    float4 bb0 = *(const float4*)(b + t * 8);
    float4 bb1 = *(const float4*)(b + t * 8 + 4);
    f16x8 o;
    o[0] = (f16)(fmaxf(acc[0] * s + bb0.x, 0.f) * sn);
    o[1] = (f16)(fmaxf(acc[1] * s + bb0.y, 0.f) * sn);
    o[2] = (f16)(fmaxf(acc[2] * s + bb0.z, 0.f) * sn);
    o[3] = (f16)(fmaxf(acc[3] * s + bb0.w, 0.f) * sn);
    o[4] = (f16)(fmaxf(acc[4] * s + bb1.x, 0.f) * sn);
    o[5] = (f16)(fmaxf(acc[5] * s + bb1.y, 0.f) * sn);
    o[6] = (f16)(fmaxf(acc[6] * s + bb1.z, 0.f) * sn);
    o[7] = (f16)(fmaxf(acc[7] * s + bb1.w, 0.f) * sn);
    *(f16x8*)(out + (long)n * HIDDEN + t * 8) = o;
  }
}

__global__ __launch_bounds__(256) void gather2_kernel(
    const f16* __restrict__ M, const int* __restrict__ rowptr,
    const int* __restrict__ col, const float* __restrict__ nd,
    const float* __restrict__ b, float* __restrict__ out) {
  constexpr int LPR = 8;        // 64 f16 = 128 B row / 16 B per lane
  constexpr int EPW = 64 / LPR; // 8 edges in parallel
  const int wave = threadIdx.x >> 6;
  const int lane = threadIdx.x & 63;
  const int eg = lane / LPR;
  const int t = lane % LPR;
  const int n = blockIdx.x * 4 + wave;
  if (n >= N_NODES) return;
  const int beg = rowptr[n];
  const int end = rowptr[n + 1];

  float acc[8];
#pragma unroll
  for (int j = 0; j < 8; ++j) acc[j] = 0.f;

  int i = beg + eg;
  for (; i + EPW < end; i += 2 * EPW) {
    int s0 = col[i];
    int s1 = col[i + EPW];
    f16x8 v0 = *(const f16x8*)(M + (long)s0 * OUT_FEATS + t * 8);
    f16x8 v1 = *(const f16x8*)(M + (long)s1 * OUT_FEATS + t * 8);
#pragma unroll
    for (int j = 0; j < 8; ++j) acc[j] += (float)v0[j] + (float)v1[j];
  }
  if (i < end) {
    int s0 = col[i];
    f16x8 v0 = *(const f16x8*)(M + (long)s0 * OUT_FEATS + t * 8);
#pragma unroll
    for (int j = 0; j < 8; ++j) acc[j] += (float)v0[j];
  }

#pragma unroll
  for (int m2 = LPR; m2 < 64; m2 <<= 1)
#pragma unroll
    for (int j = 0; j < 8; ++j) acc[j] += __shfl_xor(acc[j], m2, 64);

  if (eg == 0) {
    float s = nd[n];
    float4 bb0 = *(const float4*)(b + t * 8);
    float4 bb1 = *(const float4*)(b + t * 8 + 4);
    float4 o0, o1;
    o0.x = acc[0] * s + bb0.x;
    o0.y = acc[1] * s + bb0.y;
    o0.z = acc[2] * s + bb0.z;
    o0.w = acc[3] * s + bb0.w;
    o1.x = acc[4] * s + bb1.x;
    o1.y = acc[5] * s + bb1.y;
    o1.z = acc[6] * s + bb1.z;
    o1.w = acc[7] * s + bb1.w;
    *(float4*)(out + (long)n * OUT_FEATS + t * 8) = o0;
    *(float4*)(out + (long)n * OUT_FEATS + t * 8 + 4) = o1;
  }
}

extern "C" void kernel_launch(void* const* d_in, const int* in_sizes, int n_in,
                              void* d_out, int out_size, void* d_ws,
                              size_t ws_size, hipStream_t stream) {
  const float* x = (const float*)d_in[0];
  const int* src = (const int*)d_in[1];
  const int* dst = (const int*)d_in[2];
  const float* W1 = (const float*)d_in[3];
  const float* b1 = (const float*)d_in[4];
  const float* W2 = (const float*)d_in[5];
  const float* b2 = (const float*)d_in[6];
  float* out = (float*)d_out;

  // ---- workspace layout
  int* wi = (int*)d_ws;
  int* partial = wi;            // [256]
  int* rowptr = wi + 256;       // [50001] (pad to 50004)
  int* deg_in = wi + 50260;     // [50000]
  int* col = wi + 100260;       // [800000] -> ends at int 900260
  float* wf = (float*)d_ws + 900260;
  float* norm_src = wf;         // [50000]
  float* norm_dst = wf + 50000; // [50000]
  f16* fh = (f16*)(wf + 100000);
  f16* W1T = fh;                // [128*256]
  f16* W2T = fh + 128 * 256;    // [64*128]
  f16* m1 = fh + 128 * 256 + 64 * 128;  // [50048*128]
  f16* h1p = m1 + (long)50048 * 128;    // [50048*128]
  f16* m2 = h1p + (long)50048 * 128;    // [50048*64]

  // hist overlay on m1/h1p/m2 region: 16.8 MB < 32 MB region; dead before
  // gemm1 writes m1 (stream-ordered).
  unsigned* hist_src = (unsigned*)m1;                       // u16[NCHUNK*NBT]
  unsigned* hist_dst = hist_src + (long)NCHUNK * NBT / 2;   // u16[NCHUNK*NBT]

  const int nb_nodes = (N_NODES + 255) / 256;  // 196
  const int rowblk = (N_NODES + 63) / 64;      // 782

  // ---- degrees + norms + CSR (no global atomics)
  hist_kernel<<<NRANGE * NCHUNK, 256, 0, stream>>>(src, dst, hist_src,
                                                   hist_dst);
  reduce_kernel<<<nb_nodes, 256, 0, stream>>>(hist_src, hist_dst, deg_in,
                                              norm_src, norm_dst, partial);
  scan2<<<1, 256, 0, stream>>>(partial, nb_nodes);
  scan3<<<nb_nodes, 256, 0, stream>>>(deg_in, partial, rowptr);
  fill_csr<<<NRANGE * NCHUNK, 256, 0, stream>>>(src, dst, rowptr, hist_dst,
                                                col);
  wtrans<<<(128 * 256 + 64 * 128 + 255) / 256, 256, 0, stream>>>(W1, W2, W1T,
                                                                 W2T);

  // ---- layer 1: 64x64 tiles, 2 col-blocks -> grid 1564
  gemm_mfma<IN_FEATS, HIDDEN, 4, true>
      <<<rowblk * 2, 256, 0, stream>>>(x, W1T, norm_src, m1);
  gather1_kernel<<<(N_NODES + 3) / 4, 256, 0, stream>>>(m1, rowptr, col,
                                                        norm_dst, norm_src, b1,
                                                        h1p);

  // ---- layer 2: 64x64 tiles, 1 col-block -> grid 782
  gemm_mfma<HIDDEN, OUT_FEATS, 4, false>
      <<<rowblk, 256, 0, stream>>>(h1p, W2T, norm_src, m2);
  gather2_kernel<<<(N_NODES + 3) / 4, 256, 0, stream>>>(m2, rowptr, col,
                                                        norm_dst, b2, out);
}